// Round 5
// baseline (110.601 us; speedup 1.0000x reference)
//
#include <hip/hip_runtime.h>
#include <hip/hip_bf16.h>

// SubjectSpecificProjection: per-subject 2-layer MLP (256->512->512) + L2 normalize.
// R5: weight streaming via global_load_lds 3-buffer pipeline, counted vmcnt(8)
//     (T3/T4 minimum), ONE barrier in the 24-step K-loop (H handoff). W-tile is
//     k-slot-major so DMA dest is linear and ds_read_b128 is conflict-free.
//     ROWS=32, acc[2][4]=32 AGPR, no launch-bounds reg cap (R4 lesson: caps => spill).

#define BATCH 16384
#define EEG 256
#define CLIP 512
#define NSUB 13
#define ROWS 32

// meta layout (ints):
#define M_BCNT 0        // [64][13]
#define M_BOFF 832      // [64][13]
#define M_SOFF 1664     // [14]
#define M_COFF 1678     // [14]
#define M_TOT  1692     // [13]
#define M_IDX  1720     // [16384]

typedef unsigned short u16;
typedef __attribute__((ext_vector_type(8))) short short8;
typedef __attribute__((ext_vector_type(4))) float f32x4;

__device__ __forceinline__ u16 f2bf(float f) {
    union { float f; unsigned int u; } v; v.f = f;
    unsigned int u = v.u;
    unsigned int r = (u + 0x7FFFu + ((u >> 16) & 1u)) >> 16;   // RNE
    return (u16)r;
}

// ---- weight convert + transpose: W[s][k][n] fp32 -> Wt[s][n][k] bf16 ----
__global__ __launch_bounds__(256) void convert_transpose(
    const float* __restrict__ W1, const float* __restrict__ W2,
    u16* __restrict__ w1t, u16* __restrict__ w2t) {
    __shared__ u16 T[64][72];
    int b = blockIdx.x;
    const float* src; u16* dst; int K, N;
    int s, k0, n0;
    if (b < 416) {               // W1: 13 x (256/64)x(512/64)=32 tiles
        s = b >> 5; int t = b & 31;
        k0 = (t >> 3) << 6; n0 = (t & 7) << 6;
        K = EEG; N = CLIP;
        src = W1 + (size_t)s * EEG * CLIP;
        dst = w1t + (size_t)s * CLIP * EEG;
    } else {                     // W2: 13 x 64 tiles
        b -= 416; s = b >> 6; int t = b & 63;
        k0 = (t >> 3) << 6; n0 = (t & 7) << 6;
        K = CLIP; N = CLIP;
        src = W2 + (size_t)s * CLIP * CLIP;
        dst = w2t + (size_t)s * CLIP * CLIP;
    }
    int tid = threadIdx.x;
    int rk = tid >> 2;
    int cg = (tid & 3) << 4;
    const float4* p4 = reinterpret_cast<const float4*>(src + (size_t)(k0 + rk) * N + n0 + cg);
    #pragma unroll
    for (int jj = 0; jj < 4; ++jj) {
        float4 v = p4[jj];
        T[cg + jj * 4 + 0][rk] = f2bf(v.x);
        T[cg + jj * 4 + 1][rk] = f2bf(v.y);
        T[cg + jj * 4 + 2][rk] = f2bf(v.z);
        T[cg + jj * 4 + 3][rk] = f2bf(v.w);
    }
    __syncthreads();
    u16* q = dst + (size_t)(n0 + rk) * K + k0 + cg;
    const short8* tp = reinterpret_cast<const short8*>(&T[rk][cg]);
    reinterpret_cast<short8*>(q)[0] = tp[0];
    reinterpret_cast<short8*>(q)[1] = tp[1];
}

// ---- counting-sort bucketing ----
__global__ __launch_bounds__(256) void hist_k(const int* __restrict__ sid, int* __restrict__ meta) {
    __shared__ int h[NSUB];
    int tid = threadIdx.x;
    if (tid < NSUB) h[tid] = 0;
    __syncthreads();
    int i = blockIdx.x * 256 + tid;
    atomicAdd(&h[sid[i]], 1);
    __syncthreads();
    if (tid < NSUB) meta[M_BCNT + blockIdx.x * NSUB + tid] = h[tid];
}

__global__ __launch_bounds__(256) void scan_k(int* __restrict__ meta) {
    __shared__ int lb[64][NSUB];
    __shared__ int tot[NSUB], so[14], co[14];
    int tid = threadIdx.x;
    for (int idx = tid; idx < 64 * NSUB; idx += 256)
        lb[idx / NSUB][idx % NSUB] = meta[M_BCNT + idx];
    __syncthreads();
    if (tid < NSUB) {
        int run = 0;
        for (int b = 0; b < 64; ++b) { int c = lb[b][tid]; lb[b][tid] = run; run += c; }
        tot[tid] = run;
    }
    __syncthreads();
    if (tid == 0) {
        int off = 0, c = 0;
        for (int s = 0; s < NSUB; ++s) {
            so[s] = off; co[s] = c;
            off += tot[s]; c += (tot[s] + ROWS - 1) / ROWS;
        }
        so[NSUB] = off; co[NSUB] = c;
    }
    __syncthreads();
    for (int idx = tid; idx < 64 * NSUB; idx += 256)
        meta[M_BOFF + idx] = so[idx % NSUB] + lb[idx / NSUB][idx % NSUB];
    if (tid < 14) { meta[M_SOFF + tid] = so[tid]; meta[M_COFF + tid] = co[tid]; }
    if (tid < NSUB) meta[M_TOT + tid] = tot[tid];
}

__global__ __launch_bounds__(256) void scatter2_k(const int* __restrict__ sid, int* __restrict__ meta) {
    __shared__ int h[NSUB];
    int tid = threadIdx.x;
    if (tid < NSUB) h[tid] = 0;
    __syncthreads();
    int i = blockIdx.x * 256 + tid;
    int s = sid[i];
    int r = atomicAdd(&h[s], 1);
    meta[M_IDX + meta[M_BOFF + blockIdx.x * NSUB + s] + r] = i;
}

// ---- fused MLP with LDS-DMA weight pipeline ----
__global__ __launch_bounds__(512) void mlp_k(
    const float* __restrict__ X, const float* __restrict__ b1,
    const float* __restrict__ b2, const u16* __restrict__ w1t,
    const u16* __restrict__ w2t, const int* __restrict__ meta,
    float* __restrict__ out) {

    __shared__ u16 Xs[ROWS * 264];     // 16.9 KB
    __shared__ u16 Hs[ROWS * 520];     // 33.3 KB
    __shared__ u16 Wl[3][16384];       // 3 x 32 KB: [buf][kslot*4096 + col*8]
    __shared__ float partial[ROWS * 8];
    __shared__ float scalev[ROWS];
    __shared__ int info[4];
    __shared__ int rowidx[ROWS];
    __shared__ int cobuf[14], sobuf[14], totbuf[NSUB];

    int tid = threadIdx.x;

    // bijective XCD swizzle (m204): subject-contiguous chunks -> same XCD L2
    int nwg = gridDim.x;
    int q = nwg >> 3, r = nwg & 7;
    int xcd = blockIdx.x & 7, idx = blockIdx.x >> 3;
    int bid = (xcd < r) ? xcd * (q + 1) + idx : r * (q + 1) + (xcd - r) * q + idx;

    if (tid < 14) { cobuf[tid] = meta[M_COFF + tid]; sobuf[tid] = meta[M_SOFF + tid]; }
    if (tid < NSUB) totbuf[tid] = meta[M_TOT + tid];
    __syncthreads();
    if (tid == 0) {
        int total = cobuf[NSUB];
        if (bid < total) {
            int s = 0;
            while (s < NSUB && !(bid >= cobuf[s] && bid < cobuf[s + 1])) s++;
            int chunk = bid - cobuf[s];
            info[0] = s;
            info[1] = sobuf[s] + chunk * ROWS;
            info[2] = min(ROWS, totbuf[s] - chunk * ROWS);
        } else info[0] = -1;
    }
    __syncthreads();
    if (info[0] < 0) return;
    int s = info[0], rowbase = info[1], nrows = info[2];

    if (tid < ROWS) rowidx[tid] = meta[M_IDX + rowbase + min(tid, nrows - 1)];
    __syncthreads();

    int wave = tid >> 6;         // 0..7
    int lane = tid & 63;
    int c = lane & 15;
    int gl = lane >> 4;
    int wn0 = wave * 64;         // this wave's 64 output columns
    int colbase = wn0;

    const u16* w1s = w1t + (size_t)s * CLIP * EEG;
    const u16* w2s = w2t + (size_t)s * CLIP * CLIP;

    // stage W k-step: wave stages its own 64 cols, 4 k-slots of 8 bf16.
    // LDS dest linear (base + lane*16B); ds_read later = [gl*4096 + col*8].
#define STAGE_W(bi, base, Kd, k0s) do {                                          \
        const u16* _s = (base) + (size_t)(colbase + lane) * (Kd) + (k0s);        \
        _Pragma("unroll")                                                        \
        for (int _it = 0; _it < 4; ++_it) {                                      \
            __builtin_amdgcn_global_load_lds(                                    \
                (const __attribute__((address_space(1))) unsigned int*)(_s + _it * 8), \
                (__attribute__((address_space(3))) unsigned int*)(&Wl[bi][_it * 4096 + colbase * 8]), \
                16, 0, 0);                                                       \
        } } while (0)

    // prologue: stage steps 0,1; stage X tile; one barrier (drains, one-time)
    STAGE_W(0, w1s, EEG, 0);
    STAGE_W(1, w1s, EEG, 32);
    {
        int row = tid >> 4, l16 = tid & 15;
        const float4* xp = reinterpret_cast<const float4*>(X + (size_t)rowidx[row] * EEG);
        u16* xd = &Xs[row * 264];
        #pragma unroll
        for (int it = 0; it < 4; ++it) {
            int c4 = l16 + it * 16;
            float4 v = xp[c4];
            union { u16 u[4]; uint2 qq; } pk;
            pk.u[0] = f2bf(v.x); pk.u[1] = f2bf(v.y);
            pk.u[2] = f2bf(v.z); pk.u[3] = f2bf(v.w);
            *reinterpret_cast<uint2*>(&xd[c4 * 4]) = pk.qq;
        }
    }
    __syncthreads();

    f32x4 acc[2][4];
    #pragma unroll
    for (int mi = 0; mi < 2; ++mi)
        #pragma unroll
        for (int ni = 0; ni < 4; ++ni)
            acc[mi][ni] = (f32x4){0.f, 0.f, 0.f, 0.f};

    // 24 steps: 0..7 layer1 (K=256), 8..23 layer2 (K=512). One barrier at step 7.
    int cur = 0;                 // step % 3
    for (int step = 0; step < 24; ++step) {
        int nxt2 = step + 2;
        if (nxt2 < 24) {
            int bi = nxt2 - (nxt2 / 3) * 3;
            if (nxt2 < 8) { STAGE_W(bi, w1s, EEG, nxt2 << 5); }
            else          { STAGE_W(bi, w2s, CLIP, (nxt2 - 8) << 5); }
        }
        // counted wait: stages for step+1,step+2 (8 ops) may remain in flight
        if (step < 22)       asm volatile("s_waitcnt vmcnt(8)" ::: "memory");
        else if (step == 22) asm volatile("s_waitcnt vmcnt(4)" ::: "memory");
        else                 asm volatile("s_waitcnt vmcnt(0)" ::: "memory");

        const u16* ap; int as, k0l;
        if (step < 8) { ap = Xs; as = 264; k0l = step << 5; }
        else          { ap = Hs; as = 520; k0l = (step - 8) << 5; }

        short8 bb[4];
        #pragma unroll
        for (int ni = 0; ni < 4; ++ni)
            bb[ni] = *reinterpret_cast<const short8*>(&Wl[cur][gl * 4096 + (wn0 + ni * 16 + c) * 8]);
        short8 a0 = *reinterpret_cast<const short8*>(&ap[(c) * as + k0l + gl * 8]);
        short8 a1 = *reinterpret_cast<const short8*>(&ap[(16 + c) * as + k0l + gl * 8]);

        #pragma unroll
        for (int ni = 0; ni < 4; ++ni) {
            acc[0][ni] = __builtin_amdgcn_mfma_f32_16x16x32_bf16(a0, bb[ni], acc[0][ni], 0, 0, 0);
            acc[1][ni] = __builtin_amdgcn_mfma_f32_16x16x32_bf16(a1, bb[ni], acc[1][ni], 0, 0, 0);
        }

        if (step == 7) {
            // layer1 epilogue: bias + relu -> Hs; the ONLY in-loop barrier
            float bias1[4];
            #pragma unroll
            for (int ni = 0; ni < 4; ++ni) bias1[ni] = b1[s * CLIP + wn0 + ni * 16 + c];
            #pragma unroll
            for (int mi = 0; mi < 2; ++mi)
                #pragma unroll
                for (int ni = 0; ni < 4; ++ni)
                    #pragma unroll
                    for (int i = 0; i < 4; ++i) {
                        float h = fmaxf(acc[mi][ni][i] + bias1[ni], 0.f);
                        Hs[(mi * 16 + gl * 4 + i) * 520 + wn0 + ni * 16 + c] = f2bf(h);
                    }
            __syncthreads();
            #pragma unroll
            for (int mi = 0; mi < 2; ++mi)
                #pragma unroll
                for (int ni = 0; ni < 4; ++ni)
                    acc[mi][ni] = (f32x4){0.f, 0.f, 0.f, 0.f};
        }
        cur = (cur == 2) ? 0 : cur + 1;
    }

    // ---- epilogue: bias2 + row-norm + write ----
    float sq[2][4];
    {
        float bias2[4];
        #pragma unroll
        for (int ni = 0; ni < 4; ++ni) bias2[ni] = b2[s * CLIP + wn0 + ni * 16 + c];
        #pragma unroll
        for (int mi = 0; mi < 2; ++mi)
            #pragma unroll
            for (int i = 0; i < 4; ++i) sq[mi][i] = 0.f;
        #pragma unroll
        for (int mi = 0; mi < 2; ++mi)
            #pragma unroll
            for (int ni = 0; ni < 4; ++ni)
                #pragma unroll
                for (int i = 0; i < 4; ++i) {
                    float v = acc[mi][ni][i] + bias2[ni];
                    acc[mi][ni][i] = v;
                    sq[mi][i] += v * v;
                }
    }
    #pragma unroll
    for (int m = 1; m < 16; m <<= 1)
        #pragma unroll
        for (int mi = 0; mi < 2; ++mi)
            #pragma unroll
            for (int i = 0; i < 4; ++i)
                sq[mi][i] += __shfl_xor(sq[mi][i], m);

    if (c == 0) {
        #pragma unroll
        for (int mi = 0; mi < 2; ++mi)
            #pragma unroll
            for (int i = 0; i < 4; ++i)
                partial[(mi * 16 + gl * 4 + i) * 8 + wave] = sq[mi][i];
    }
    __syncthreads();
    if (tid < ROWS) {
        float t = 0.f;
        #pragma unroll
        for (int w = 0; w < 8; ++w) t += partial[tid * 8 + w];
        scalev[tid] = 1.f / fmaxf(sqrtf(t), 1e-12f);
    }
    __syncthreads();

    #pragma unroll
    for (int mi = 0; mi < 2; ++mi)
        #pragma unroll
        for (int i = 0; i < 4; ++i) {
            int row = mi * 16 + gl * 4 + i;
            if (row < nrows) {
                float sc = scalev[row];
                float* op = out + (size_t)rowidx[row] * CLIP + wn0 + c;
                #pragma unroll
                for (int ni = 0; ni < 4; ++ni)
                    op[ni * 16] = acc[mi][ni][i] * sc;
            }
        }
#undef STAGE_W
}

extern "C" void kernel_launch(void* const* d_in, const int* in_sizes, int n_in,
                              void* d_out, int out_size, void* d_ws, size_t ws_size,
                              hipStream_t stream) {
    const float* eeg = (const float*)d_in[0];
    const int* sid   = (const int*)d_in[1];
    const float* W1  = (const float*)d_in[2];
    const float* b1  = (const float*)d_in[3];
    const float* W2  = (const float*)d_in[4];
    const float* b2  = (const float*)d_in[5];
    float* out = (float*)d_out;

    u16* w1t = (u16*)d_ws;
    u16* w2t = w1t + (size_t)NSUB * CLIP * EEG;
    int* meta = (int*)(w2t + (size_t)NSUB * CLIP * CLIP);

    convert_transpose<<<1248, 256, 0, stream>>>(W1, W2, w1t, w2t);
    hist_k<<<BATCH / 256, 256, 0, stream>>>(sid, meta);
    scan_k<<<1, 256, 0, stream>>>(meta);
    scatter2_k<<<BATCH / 256, 256, 0, stream>>>(sid, meta);
    mlp_k<<<BATCH / ROWS + NSUB, 512, 0, stream>>>(eeg, b1, b2, w1t, w2t, meta, out);
}

// Round 6
// 87.307 us; speedup vs baseline: 1.2668x; 1.2668x over previous
//
#include <hip/hip_runtime.h>
#include <hip/hip_bf16.h>

// SubjectSpecificProjection: per-subject 2-layer MLP (256->512->512) + L2 normalize.
// R6: LAYER SPLIT. Model from R1-R5: per-CU fetch ~25 GB/s (L1-miss-slot bound),
//     fused floor = 786KB weights/block @ M=64 -> ~32us/block. Split:
//     K1: H=relu(X@W1+b1), M=128 x Npanel=256 -> 262 KB/block, H bf16 to ws (sorted).
//     K2: Y=H@W2+b2 + norm + scatter, M=64 full-N (norm couples N) -> 576 KB/block.

#define BATCH 16384
#define EEG 256
#define CLIP 512
#define NSUB 13

// meta layout (ints):
#define M_BCNT 0        // [64][13]
#define M_BOFF 832      // [64][13]
#define M_SOFF 1664     // [14] sample offsets per subject
#define M_COFF 1678     // [14] 64-row chunk offsets
#define M_TOT  1692     // [13] per-subject counts
#define M_C128 1705     // [14] 128-row chunk offsets
#define M_IDX  1720     // [16384] sorted sample indices

typedef unsigned short u16;
typedef __attribute__((ext_vector_type(8))) short short8;
typedef __attribute__((ext_vector_type(4))) float f32x4;

__device__ __forceinline__ u16 f2bf(float f) {
    union { float f; unsigned int u; } v; v.f = f;
    unsigned int u = v.u;
    unsigned int r = (u + 0x7FFFu + ((u >> 16) & 1u)) >> 16;   // RNE
    return (u16)r;
}

// ---- weight convert + transpose: W[s][k][n] fp32 -> Wt[s][n][k] bf16 ----
__global__ __launch_bounds__(256) void convert_transpose(
    const float* __restrict__ W1, const float* __restrict__ W2,
    u16* __restrict__ w1t, u16* __restrict__ w2t) {
    __shared__ u16 T[64][72];
    int b = blockIdx.x;
    const float* src; u16* dst; int K, N;
    int s, k0, n0;
    if (b < 416) {               // W1: 13 x (256/64)x(512/64)=32 tiles
        s = b >> 5; int t = b & 31;
        k0 = (t >> 3) << 6; n0 = (t & 7) << 6;
        K = EEG; N = CLIP;
        src = W1 + (size_t)s * EEG * CLIP;
        dst = w1t + (size_t)s * CLIP * EEG;
    } else {                     // W2: 13 x 64 tiles
        b -= 416; s = b >> 6; int t = b & 63;
        k0 = (t >> 3) << 6; n0 = (t & 7) << 6;
        K = CLIP; N = CLIP;
        src = W2 + (size_t)s * CLIP * CLIP;
        dst = w2t + (size_t)s * CLIP * CLIP;
    }
    int tid = threadIdx.x;
    int rk = tid >> 2;
    int cg = (tid & 3) << 4;
    const float4* p4 = reinterpret_cast<const float4*>(src + (size_t)(k0 + rk) * N + n0 + cg);
    #pragma unroll
    for (int jj = 0; jj < 4; ++jj) {
        float4 v = p4[jj];
        T[cg + jj * 4 + 0][rk] = f2bf(v.x);
        T[cg + jj * 4 + 1][rk] = f2bf(v.y);
        T[cg + jj * 4 + 2][rk] = f2bf(v.z);
        T[cg + jj * 4 + 3][rk] = f2bf(v.w);
    }
    __syncthreads();
    u16* qd = dst + (size_t)(n0 + rk) * K + k0 + cg;
    const short8* tp = reinterpret_cast<const short8*>(&T[rk][cg]);
    reinterpret_cast<short8*>(qd)[0] = tp[0];
    reinterpret_cast<short8*>(qd)[1] = tp[1];
}

// ---- counting-sort bucketing ----
__global__ __launch_bounds__(256) void hist_k(const int* __restrict__ sid, int* __restrict__ meta) {
    __shared__ int h[NSUB];
    int tid = threadIdx.x;
    if (tid < NSUB) h[tid] = 0;
    __syncthreads();
    int i = blockIdx.x * 256 + tid;
    atomicAdd(&h[sid[i]], 1);
    __syncthreads();
    if (tid < NSUB) meta[M_BCNT + blockIdx.x * NSUB + tid] = h[tid];
}

__global__ __launch_bounds__(256) void scan_k(int* __restrict__ meta) {
    __shared__ int lb[64][NSUB];
    __shared__ int tot[NSUB], so[14], co[14], c1[14];
    int tid = threadIdx.x;
    for (int idx = tid; idx < 64 * NSUB; idx += 256)
        lb[idx / NSUB][idx % NSUB] = meta[M_BCNT + idx];
    __syncthreads();
    if (tid < NSUB) {
        int run = 0;
        for (int b = 0; b < 64; ++b) { int c = lb[b][tid]; lb[b][tid] = run; run += c; }
        tot[tid] = run;
    }
    __syncthreads();
    if (tid == 0) {
        int off = 0, c64 = 0, c128 = 0;
        for (int s = 0; s < NSUB; ++s) {
            so[s] = off; co[s] = c64; c1[s] = c128;
            off += tot[s];
            c64 += (tot[s] + 63) / 64;
            c128 += (tot[s] + 127) / 128;
        }
        so[NSUB] = off; co[NSUB] = c64; c1[NSUB] = c128;
    }
    __syncthreads();
    for (int idx = tid; idx < 64 * NSUB; idx += 256)
        meta[M_BOFF + idx] = so[idx % NSUB] + lb[idx / NSUB][idx % NSUB];
    if (tid < 14) {
        meta[M_SOFF + tid] = so[tid];
        meta[M_COFF + tid] = co[tid];
        meta[M_C128 + tid] = c1[tid];
    }
    if (tid < NSUB) meta[M_TOT + tid] = tot[tid];
}

__global__ __launch_bounds__(256) void scatter2_k(const int* __restrict__ sid, int* __restrict__ meta) {
    __shared__ int h[NSUB];
    int tid = threadIdx.x;
    if (tid < NSUB) h[tid] = 0;
    __syncthreads();
    int i = blockIdx.x * 256 + tid;
    int s = sid[i];
    int r = atomicAdd(&h[s], 1);
    meta[M_IDX + meta[M_BOFF + blockIdx.x * NSUB + s] + r] = i;
}

// ---- K1: H = relu(X @ W1 + b1), M=128 x Npanel=256, H bf16 in sorted order ----
__global__ __launch_bounds__(512) void gemm1_k(
    const float* __restrict__ X, const float* __restrict__ b1,
    const u16* __restrict__ w1t, const int* __restrict__ meta,
    u16* __restrict__ H) {

    __shared__ u16 Xc[128 * 72];       // 18.4 KB: one 64-wide K-chunk, 128 rows
    __shared__ int info[4];
    __shared__ int rowidx[128];
    __shared__ int cobuf[14], sobuf[14], totbuf[NSUB];

    int tid = threadIdx.x;

    // bijective XCD swizzle; panel pairs stay adjacent -> same XCD L2
    int nwg = gridDim.x;
    int q = nwg >> 3, r = nwg & 7;
    int xcd = blockIdx.x & 7, idx = blockIdx.x >> 3;
    int bid = (xcd < r) ? xcd * (q + 1) + idx : r * (q + 1) + (xcd - r) * q + idx;
    int chunk = bid >> 1, panel = bid & 1;

    if (tid < 14) { cobuf[tid] = meta[M_C128 + tid]; sobuf[tid] = meta[M_SOFF + tid]; }
    if (tid < NSUB) totbuf[tid] = meta[M_TOT + tid];
    __syncthreads();
    if (tid == 0) {
        int total = cobuf[NSUB];
        if (chunk < total) {
            int s = 0;
            while (s < NSUB && !(chunk >= cobuf[s] && chunk < cobuf[s + 1])) s++;
            int ch = chunk - cobuf[s];
            info[0] = s;
            info[1] = sobuf[s] + ch * 128;
            info[2] = min(128, totbuf[s] - ch * 128);
        } else info[0] = -1;
    }
    __syncthreads();
    if (info[0] < 0) return;
    int s = info[0], rowbase = info[1], nrows = info[2];
    if (tid < 128) rowidx[tid] = meta[M_IDX + rowbase + min(tid, nrows - 1)];
    // first loop-top barrier covers rowidx

    int wave = tid >> 6, lane = tid & 63;
    int c = lane & 15, gl = lane >> 4;
    int wm = wave >> 2, wn = wave & 3;     // 2M x 4N wave grid
    int col0 = panel * 256 + wn * 64;      // wave's col base in CLIP

    f32x4 acc[4][4];
    #pragma unroll
    for (int mi = 0; mi < 4; ++mi)
        #pragma unroll
        for (int ni = 0; ni < 4; ++ni)
            acc[mi][ni] = (f32x4){0.f, 0.f, 0.f, 0.f};

    const u16* w1s = w1t + (size_t)s * CLIP * EEG;
    int srow = tid >> 2, sl4 = tid & 3;

    for (int kc = 0; kc < 4; ++kc) {
        __syncthreads();
        {   // stage 128x64 X chunk, fp32 -> bf16
            const float4* xp = reinterpret_cast<const float4*>(
                X + (size_t)rowidx[srow] * EEG) + kc * 16 + sl4 * 4;
            u16* xd = &Xc[srow * 72 + sl4 * 16];
            #pragma unroll
            for (int j = 0; j < 4; ++j) {
                float4 v = xp[j];
                union { u16 u[4]; uint2 qq; } pk;
                pk.u[0] = f2bf(v.x); pk.u[1] = f2bf(v.y);
                pk.u[2] = f2bf(v.z); pk.u[3] = f2bf(v.w);
                *reinterpret_cast<uint2*>(&xd[j * 4]) = pk.qq;
            }
        }
        __syncthreads();
        #pragma unroll
        for (int k0 = 0; k0 < 64; k0 += 32) {
            short8 a[4], bb[4];
            #pragma unroll
            for (int ni = 0; ni < 4; ++ni)
                bb[ni] = *reinterpret_cast<const short8*>(
                    &w1s[(size_t)(col0 + ni * 16 + c) * EEG + kc * 64 + k0 + gl * 8]);
            #pragma unroll
            for (int mi = 0; mi < 4; ++mi)
                a[mi] = *reinterpret_cast<const short8*>(&Xc[(wm * 64 + mi * 16 + c) * 72 + k0 + gl * 8]);
            #pragma unroll
            for (int mi = 0; mi < 4; ++mi)
                #pragma unroll
                for (int ni = 0; ni < 4; ++ni)
                    acc[mi][ni] = __builtin_amdgcn_mfma_f32_16x16x32_bf16(a[mi], bb[ni], acc[mi][ni], 0, 0, 0);
        }
    }

    // epilogue: bias + relu -> H (sorted order, guarded rows)
    float bias1[4];
    #pragma unroll
    for (int ni = 0; ni < 4; ++ni) bias1[ni] = b1[s * CLIP + col0 + ni * 16 + c];
    #pragma unroll
    for (int mi = 0; mi < 4; ++mi)
        #pragma unroll
        for (int i = 0; i < 4; ++i) {
            int rl = wm * 64 + mi * 16 + gl * 4 + i;
            if (rl < nrows) {
                u16* hp = H + (size_t)(rowbase + rl) * CLIP + col0 + c;
                #pragma unroll
                for (int ni = 0; ni < 4; ++ni) {
                    float h = fmaxf(acc[mi][ni][i] + bias1[ni], 0.f);
                    hp[ni * 16] = f2bf(h);
                }
            }
        }
}

// ---- K2: Y = H @ W2 + b2, L2-normalize rows, scatter to out. M=64, full N ----
__global__ __launch_bounds__(512) void gemm2_k(
    const float* __restrict__ b2, const u16* __restrict__ w2t,
    const int* __restrict__ meta, const u16* __restrict__ H,
    float* __restrict__ out) {

    __shared__ u16 Hs[64 * 520];       // 66.6 KB
    __shared__ float partial[64 * 8];
    __shared__ float scalev[64];
    __shared__ int info[4];
    __shared__ int rowidx[64];
    __shared__ int cobuf[14], sobuf[14], totbuf[NSUB];

    int tid = threadIdx.x;

    int nwg = gridDim.x;
    int q = nwg >> 3, r = nwg & 7;
    int xcd = blockIdx.x & 7, idx = blockIdx.x >> 3;
    int bid = (xcd < r) ? xcd * (q + 1) + idx : r * (q + 1) + (xcd - r) * q + idx;

    if (tid < 14) { cobuf[tid] = meta[M_COFF + tid]; sobuf[tid] = meta[M_SOFF + tid]; }
    if (tid < NSUB) totbuf[tid] = meta[M_TOT + tid];
    __syncthreads();
    if (tid == 0) {
        int total = cobuf[NSUB];
        if (bid < total) {
            int s = 0;
            while (s < NSUB && !(bid >= cobuf[s] && bid < cobuf[s + 1])) s++;
            int chunk = bid - cobuf[s];
            info[0] = s;
            info[1] = sobuf[s] + chunk * 64;
            info[2] = min(64, totbuf[s] - chunk * 64);
        } else info[0] = -1;
    }
    __syncthreads();
    if (info[0] < 0) return;
    int s = info[0], rowbase = info[1], nrows = info[2];

    if (tid < 64) rowidx[tid] = meta[M_IDX + rowbase + min(tid, nrows - 1)];

    // stage H tile (sorted rows -> coalesced bf16 reads)
    {
        int row = tid >> 3, l8 = tid & 7;
        int hrow = rowbase + min(row, nrows - 1);   // clamp: don't read past subject/H end
        const short8* hp = reinterpret_cast<const short8*>(H + (size_t)hrow * CLIP);
        #pragma unroll
        for (int it = 0; it < 8; ++it) {
            int cg = l8 + it * 8;
            *reinterpret_cast<short8*>(&Hs[row * 520 + cg * 8]) = hp[cg];
        }
    }
    __syncthreads();   // covers rowidx + Hs

    int wave = tid >> 6;
    int lane = tid & 63;
    int c = lane & 15;
    int gl = lane >> 4;
    int wn0 = wave * 64;

    f32x4 acc2[4][4];
    #pragma unroll
    for (int mi = 0; mi < 4; ++mi)
        #pragma unroll
        for (int ni = 0; ni < 4; ++ni)
            acc2[mi][ni] = (f32x4){0.f, 0.f, 0.f, 0.f};

    const u16* w2s = w2t + (size_t)s * CLIP * CLIP;
    #pragma unroll 4
    for (int k0 = 0; k0 < CLIP; k0 += 32) {
        short8 a[4], bb[4];
        #pragma unroll
        for (int ni = 0; ni < 4; ++ni)
            bb[ni] = *reinterpret_cast<const short8*>(
                &w2s[(size_t)(wn0 + ni * 16 + c) * CLIP + k0 + gl * 8]);
        #pragma unroll
        for (int mi = 0; mi < 4; ++mi)
            a[mi] = *reinterpret_cast<const short8*>(&Hs[(mi * 16 + c) * 520 + k0 + gl * 8]);
        #pragma unroll
        for (int mi = 0; mi < 4; ++mi)
            #pragma unroll
            for (int ni = 0; ni < 4; ++ni)
                acc2[mi][ni] = __builtin_amdgcn_mfma_f32_16x16x32_bf16(a[mi], bb[ni], acc2[mi][ni], 0, 0, 0);
    }

    // bias + squared row-sums (this wave's 64 cols)
    float sq[4][4];
    {
        float bias2[4];
        #pragma unroll
        for (int ni = 0; ni < 4; ++ni) bias2[ni] = b2[s * CLIP + wn0 + ni * 16 + c];
        #pragma unroll
        for (int mi = 0; mi < 4; ++mi)
            #pragma unroll
            for (int i = 0; i < 4; ++i) sq[mi][i] = 0.f;
        #pragma unroll
        for (int mi = 0; mi < 4; ++mi)
            #pragma unroll
            for (int ni = 0; ni < 4; ++ni)
                #pragma unroll
                for (int i = 0; i < 4; ++i) {
                    float v = acc2[mi][ni][i] + bias2[ni];
                    acc2[mi][ni][i] = v;
                    sq[mi][i] += v * v;
                }
    }
    #pragma unroll
    for (int m = 1; m < 16; m <<= 1)
        #pragma unroll
        for (int mi = 0; mi < 4; ++mi)
            #pragma unroll
            for (int i = 0; i < 4; ++i)
                sq[mi][i] += __shfl_xor(sq[mi][i], m);

    if (c == 0) {
        #pragma unroll
        for (int mi = 0; mi < 4; ++mi)
            #pragma unroll
            for (int i = 0; i < 4; ++i)
                partial[(mi * 16 + gl * 4 + i) * 8 + wave] = sq[mi][i];
    }
    __syncthreads();
    if (tid < 64) {
        float t = 0.f;
        #pragma unroll
        for (int w = 0; w < 8; ++w) t += partial[tid * 8 + w];
        scalev[tid] = 1.f / fmaxf(sqrtf(t), 1e-12f);
    }
    __syncthreads();

    #pragma unroll
    for (int mi = 0; mi < 4; ++mi)
        #pragma unroll
        for (int i = 0; i < 4; ++i) {
            int row = mi * 16 + gl * 4 + i;
            if (row < nrows) {
                float sc = scalev[row];
                float* op = out + (size_t)rowidx[row] * CLIP + wn0 + c;
                #pragma unroll
                for (int ni = 0; ni < 4; ++ni)
                    op[ni * 16] = acc2[mi][ni][i] * sc;
            }
        }
}

extern "C" void kernel_launch(void* const* d_in, const int* in_sizes, int n_in,
                              void* d_out, int out_size, void* d_ws, size_t ws_size,
                              hipStream_t stream) {
    const float* eeg = (const float*)d_in[0];
    const int* sid   = (const int*)d_in[1];
    const float* W1  = (const float*)d_in[2];
    const float* b1  = (const float*)d_in[3];
    const float* W2  = (const float*)d_in[4];
    const float* b2  = (const float*)d_in[5];
    float* out = (float*)d_out;

    u16* w1t = (u16*)d_ws;                                   // 3.4 MB
    u16* w2t = w1t + (size_t)NSUB * CLIP * EEG;              // 6.8 MB
    u16* Hbuf = w2t + (size_t)NSUB * CLIP * CLIP;            // 16.8 MB (sorted order)
    int* meta = (int*)(Hbuf + (size_t)BATCH * CLIP);         // ~72 KB

    convert_transpose<<<1248, 256, 0, stream>>>(W1, W2, w1t, w2t);
    hist_k<<<BATCH / 256, 256, 0, stream>>>(sid, meta);
    scan_k<<<1, 256, 0, stream>>>(meta);
    scatter2_k<<<BATCH / 256, 256, 0, stream>>>(sid, meta);
    gemm1_k<<<(BATCH / 128 + NSUB) * 2, 512, 0, stream>>>(eeg, b1, w1t, meta, Hbuf);
    gemm2_k<<<BATCH / 64 + NSUB, 512, 0, stream>>>(b2, w2t, meta, Hbuf, out);
}

// Round 7
// 65.814 us; speedup vs baseline: 1.6805x; 1.3266x over previous
//
#include <hip/hip_runtime.h>
#include <hip/hip_bf16.h>

// SubjectSpecificProjection: per-subject 2-layer MLP (256->512->512) + L2 normalize.
// R7: CONSUMPTION-ORDERED WEIGHT PACKING. R1-R6 fit a ~25-27 GB/s/CU fetch law;
//     hypothesis: caused by 512-1024B power-of-2-strided line streams in the
//     [col][k] weight layout (L2-channel contention, no prefetch). Repack weights
//     per (subject, 64-col group, 32-k step) into contiguous 4KB chunks
//     [kslot(4)][col(64)][8bf16] so each wave streams sequential contiguous chunks.
//     Everything else identical to R6 for attribution.

#define BATCH 16384
#define EEG 256
#define CLIP 512
#define NSUB 13

// meta layout (ints):
#define M_BCNT 0        // [64][13]
#define M_BOFF 832      // [64][13]
#define M_SOFF 1664     // [14] sample offsets per subject
#define M_COFF 1678     // [14] 64-row chunk offsets
#define M_TOT  1692     // [13] per-subject counts
#define M_C128 1705     // [14] 128-row chunk offsets
#define M_IDX  1720     // [16384] sorted sample indices

typedef unsigned short u16;
typedef __attribute__((ext_vector_type(8))) short short8;
typedef __attribute__((ext_vector_type(4))) float f32x4;

__device__ __forceinline__ u16 f2bf(float f) {
    union { float f; unsigned int u; } v; v.f = f;
    unsigned int u = v.u;
    unsigned int r = (u + 0x7FFFu + ((u >> 16) & 1u)) >> 16;   // RNE
    return (u16)r;
}

// ---- weight convert + pack: W[s][k][n] fp32 -> packed bf16 chunks ----
// chunk(s,g,t) = 2048 u16 laid [slot(4)][colin(64)][e(8)], element =
//   W[s][k = t*32 + slot*8 + e][n = g*64 + colin].
// W1: chunk offset ((s*8+g)*8  + t)*2048   (8 k-steps)
// W2: chunk offset ((s*8+g)*16 + t)*2048   (16 k-steps)
__global__ __launch_bounds__(256) void convert_pack(
    const float* __restrict__ W1, const float* __restrict__ W2,
    u16* __restrict__ w1p, u16* __restrict__ w2p) {
    __shared__ u16 T[64][72];          // [n-within][k-within]
    int b = blockIdx.x;
    const float* src; u16* dstbase; int N, ksteps;
    int s, kt, g;
    if (b < 416) {                     // W1: 13 x (4 kt)x(8 g)
        s = b >> 5; int t = b & 31;
        kt = t >> 3; g = t & 7;
        N = CLIP; ksteps = 8;
        src = W1 + (size_t)s * EEG * CLIP;
        dstbase = w1p + (size_t)s * CLIP * EEG;
    } else {                           // W2: 13 x (8 kt)x(8 g)
        b -= 416; s = b >> 6; int t = b & 63;
        kt = t >> 3; g = t & 7;
        N = CLIP; ksteps = 16;
        src = W2 + (size_t)s * CLIP * CLIP;
        dstbase = w2p + (size_t)s * CLIP * CLIP;
    }
    int k0 = kt << 6, n0 = g << 6;
    int tid = threadIdx.x;
    int rk = tid >> 2;                 // k row 0..63
    int cg = (tid & 3) << 4;           // n col group
    const float4* p4 = reinterpret_cast<const float4*>(src + (size_t)(k0 + rk) * N + n0 + cg);
    #pragma unroll
    for (int jj = 0; jj < 4; ++jj) {
        float4 v = p4[jj];
        T[cg + jj * 4 + 0][rk] = f2bf(v.x);
        T[cg + jj * 4 + 1][rk] = f2bf(v.y);
        T[cg + jj * 4 + 2][rk] = f2bf(v.z);
        T[cg + jj * 4 + 3][rk] = f2bf(v.w);
    }
    __syncthreads();
    // packed write: this 64x64 tile covers k-steps t = kt*2, kt*2+1
    int colin = tid & 63, sl = (tid >> 6) & 3;
    #pragma unroll
    for (int half = 0; half < 2; ++half) {
        int t = kt * 2 + half;
        u16* dst = dstbase + ((size_t)(g * ksteps + t)) * 2048 + sl * 512 + colin * 8;
        *reinterpret_cast<short8*>(dst) =
            *reinterpret_cast<const short8*>(&T[colin][half * 32 + sl * 8]);
    }
}

// ---- counting-sort bucketing ----
__global__ __launch_bounds__(256) void hist_k(const int* __restrict__ sid, int* __restrict__ meta) {
    __shared__ int h[NSUB];
    int tid = threadIdx.x;
    if (tid < NSUB) h[tid] = 0;
    __syncthreads();
    int i = blockIdx.x * 256 + tid;
    atomicAdd(&h[sid[i]], 1);
    __syncthreads();
    if (tid < NSUB) meta[M_BCNT + blockIdx.x * NSUB + tid] = h[tid];
}

__global__ __launch_bounds__(256) void scan_k(int* __restrict__ meta) {
    __shared__ int lb[64][NSUB];
    __shared__ int tot[NSUB], so[14], co[14], c1[14];
    int tid = threadIdx.x;
    for (int idx = tid; idx < 64 * NSUB; idx += 256)
        lb[idx / NSUB][idx % NSUB] = meta[M_BCNT + idx];
    __syncthreads();
    if (tid < NSUB) {
        int run = 0;
        for (int b = 0; b < 64; ++b) { int c = lb[b][tid]; lb[b][tid] = run; run += c; }
        tot[tid] = run;
    }
    __syncthreads();
    if (tid == 0) {
        int off = 0, c64 = 0, c128 = 0;
        for (int s = 0; s < NSUB; ++s) {
            so[s] = off; co[s] = c64; c1[s] = c128;
            off += tot[s];
            c64 += (tot[s] + 63) / 64;
            c128 += (tot[s] + 127) / 128;
        }
        so[NSUB] = off; co[NSUB] = c64; c1[NSUB] = c128;
    }
    __syncthreads();
    for (int idx = tid; idx < 64 * NSUB; idx += 256)
        meta[M_BOFF + idx] = so[idx % NSUB] + lb[idx / NSUB][idx % NSUB];
    if (tid < 14) {
        meta[M_SOFF + tid] = so[tid];
        meta[M_COFF + tid] = co[tid];
        meta[M_C128 + tid] = c1[tid];
    }
    if (tid < NSUB) meta[M_TOT + tid] = tot[tid];
}

__global__ __launch_bounds__(256) void scatter2_k(const int* __restrict__ sid, int* __restrict__ meta) {
    __shared__ int h[NSUB];
    int tid = threadIdx.x;
    if (tid < NSUB) h[tid] = 0;
    __syncthreads();
    int i = blockIdx.x * 256 + tid;
    int s = sid[i];
    int r = atomicAdd(&h[s], 1);
    meta[M_IDX + meta[M_BOFF + blockIdx.x * NSUB + s] + r] = i;
}

// ---- K1: H = relu(X @ W1 + b1), M=128 x Npanel=256, H bf16 in sorted order ----
__global__ __launch_bounds__(512) void gemm1_k(
    const float* __restrict__ X, const float* __restrict__ b1,
    const u16* __restrict__ w1p, const int* __restrict__ meta,
    u16* __restrict__ H) {

    __shared__ u16 Xc[128 * 72];       // 18.4 KB: one 64-wide K-chunk, 128 rows
    __shared__ int info[4];
    __shared__ int rowidx[128];
    __shared__ int cobuf[14], sobuf[14], totbuf[NSUB];

    int tid = threadIdx.x;

    int nwg = gridDim.x;
    int q = nwg >> 3, r = nwg & 7;
    int xcd = blockIdx.x & 7, idx = blockIdx.x >> 3;
    int bid = (xcd < r) ? xcd * (q + 1) + idx : r * (q + 1) + (xcd - r) * q + idx;
    int chunk = bid >> 1, panel = bid & 1;

    if (tid < 14) { cobuf[tid] = meta[M_C128 + tid]; sobuf[tid] = meta[M_SOFF + tid]; }
    if (tid < NSUB) totbuf[tid] = meta[M_TOT + tid];
    __syncthreads();
    if (tid == 0) {
        int total = cobuf[NSUB];
        if (chunk < total) {
            int s = 0;
            while (s < NSUB && !(chunk >= cobuf[s] && chunk < cobuf[s + 1])) s++;
            int ch = chunk - cobuf[s];
            info[0] = s;
            info[1] = sobuf[s] + ch * 128;
            info[2] = min(128, totbuf[s] - ch * 128);
        } else info[0] = -1;
    }
    __syncthreads();
    if (info[0] < 0) return;
    int s = info[0], rowbase = info[1], nrows = info[2];
    if (tid < 128) rowidx[tid] = meta[M_IDX + rowbase + min(tid, nrows - 1)];

    int wave = tid >> 6, lane = tid & 63;
    int c = lane & 15, gl = lane >> 4;
    int wm = wave >> 2, wn = wave & 3;     // 2M x 4N wave grid
    int col0 = panel * 256 + wn * 64;
    // packed: this wave's chunks for group g = col0>>6, 8 k-steps
    const u16* w1c = w1p + (size_t)s * CLIP * EEG + (size_t)(col0 >> 6) * 8 * 2048;

    f32x4 acc[4][4];
    #pragma unroll
    for (int mi = 0; mi < 4; ++mi)
        #pragma unroll
        for (int ni = 0; ni < 4; ++ni)
            acc[mi][ni] = (f32x4){0.f, 0.f, 0.f, 0.f};

    int srow = tid >> 2, sl4 = tid & 3;

    for (int kc = 0; kc < 4; ++kc) {
        __syncthreads();
        {   // stage 128x64 X chunk, fp32 -> bf16
            const float4* xp = reinterpret_cast<const float4*>(
                X + (size_t)rowidx[srow] * EEG) + kc * 16 + sl4 * 4;
            u16* xd = &Xc[srow * 72 + sl4 * 16];
            #pragma unroll
            for (int j = 0; j < 4; ++j) {
                float4 v = xp[j];
                union { u16 u[4]; uint2 qq; } pk;
                pk.u[0] = f2bf(v.x); pk.u[1] = f2bf(v.y);
                pk.u[2] = f2bf(v.z); pk.u[3] = f2bf(v.w);
                *reinterpret_cast<uint2*>(&xd[j * 4]) = pk.qq;
            }
        }
        __syncthreads();
        #pragma unroll
        for (int k0 = 0; k0 < 64; k0 += 32) {
            int t = kc * 2 + (k0 >> 5);
            short8 a[4], bb[4];
            #pragma unroll
            for (int ni = 0; ni < 4; ++ni)
                bb[ni] = *reinterpret_cast<const short8*>(
                    &w1c[(size_t)t * 2048 + gl * 512 + (ni * 16 + c) * 8]);
            #pragma unroll
            for (int mi = 0; mi < 4; ++mi)
                a[mi] = *reinterpret_cast<const short8*>(&Xc[(wm * 64 + mi * 16 + c) * 72 + k0 + gl * 8]);
            #pragma unroll
            for (int mi = 0; mi < 4; ++mi)
                #pragma unroll
                for (int ni = 0; ni < 4; ++ni)
                    acc[mi][ni] = __builtin_amdgcn_mfma_f32_16x16x32_bf16(a[mi], bb[ni], acc[mi][ni], 0, 0, 0);
        }
    }

    // epilogue: bias + relu -> H (sorted order, guarded rows)
    float bias1[4];
    #pragma unroll
    for (int ni = 0; ni < 4; ++ni) bias1[ni] = b1[s * CLIP + col0 + ni * 16 + c];
    #pragma unroll
    for (int mi = 0; mi < 4; ++mi)
        #pragma unroll
        for (int i = 0; i < 4; ++i) {
            int rl = wm * 64 + mi * 16 + gl * 4 + i;
            if (rl < nrows) {
                u16* hp = H + (size_t)(rowbase + rl) * CLIP + col0 + c;
                #pragma unroll
                for (int ni = 0; ni < 4; ++ni) {
                    float h = fmaxf(acc[mi][ni][i] + bias1[ni], 0.f);
                    hp[ni * 16] = f2bf(h);
                }
            }
        }
}

// ---- K2: Y = H @ W2 + b2, L2-normalize rows, scatter to out. M=64, full N ----
__global__ __launch_bounds__(512) void gemm2_k(
    const float* __restrict__ b2, const u16* __restrict__ w2p,
    const int* __restrict__ meta, const u16* __restrict__ H,
    float* __restrict__ out) {

    __shared__ u16 Hs[64 * 520];       // 66.6 KB
    __shared__ float partial[64 * 8];
    __shared__ float scalev[64];
    __shared__ int info[4];
    __shared__ int rowidx[64];
    __shared__ int cobuf[14], sobuf[14], totbuf[NSUB];

    int tid = threadIdx.x;

    int nwg = gridDim.x;
    int q = nwg >> 3, r = nwg & 7;
    int xcd = blockIdx.x & 7, idx = blockIdx.x >> 3;
    int bid = (xcd < r) ? xcd * (q + 1) + idx : r * (q + 1) + (xcd - r) * q + idx;

    if (tid < 14) { cobuf[tid] = meta[M_COFF + tid]; sobuf[tid] = meta[M_SOFF + tid]; }
    if (tid < NSUB) totbuf[tid] = meta[M_TOT + tid];
    __syncthreads();
    if (tid == 0) {
        int total = cobuf[NSUB];
        if (bid < total) {
            int s = 0;
            while (s < NSUB && !(bid >= cobuf[s] && bid < cobuf[s + 1])) s++;
            int chunk = bid - cobuf[s];
            info[0] = s;
            info[1] = sobuf[s] + chunk * 64;
            info[2] = min(64, totbuf[s] - chunk * 64);
        } else info[0] = -1;
    }
    __syncthreads();
    if (info[0] < 0) return;
    int s = info[0], rowbase = info[1], nrows = info[2];

    if (tid < 64) rowidx[tid] = meta[M_IDX + rowbase + min(tid, nrows - 1)];

    // stage H tile (sorted rows -> coalesced bf16 reads)
    {
        int row = tid >> 3, l8 = tid & 7;
        int hrow = rowbase + min(row, nrows - 1);
        const short8* hp = reinterpret_cast<const short8*>(H + (size_t)hrow * CLIP);
        #pragma unroll
        for (int it = 0; it < 8; ++it) {
            int cg = l8 + it * 8;
            *reinterpret_cast<short8*>(&Hs[row * 520 + cg * 8]) = hp[cg];
        }
    }
    __syncthreads();

    int wave = tid >> 6;
    int lane = tid & 63;
    int c = lane & 15;
    int gl = lane >> 4;
    int wn0 = wave * 64;
    const u16* w2c = w2p + (size_t)s * CLIP * CLIP + (size_t)(wn0 >> 6) * 16 * 2048;

    f32x4 acc2[4][4];
    #pragma unroll
    for (int mi = 0; mi < 4; ++mi)
        #pragma unroll
        for (int ni = 0; ni < 4; ++ni)
            acc2[mi][ni] = (f32x4){0.f, 0.f, 0.f, 0.f};

    #pragma unroll 4
    for (int k0 = 0; k0 < CLIP; k0 += 32) {
        int t = k0 >> 5;
        short8 a[4], bb[4];
        #pragma unroll
        for (int ni = 0; ni < 4; ++ni)
            bb[ni] = *reinterpret_cast<const short8*>(
                &w2c[(size_t)t * 2048 + gl * 512 + (ni * 16 + c) * 8]);
        #pragma unroll
        for (int mi = 0; mi < 4; ++mi)
            a[mi] = *reinterpret_cast<const short8*>(&Hs[(mi * 16 + c) * 520 + k0 + gl * 8]);
        #pragma unroll
        for (int mi = 0; mi < 4; ++mi)
            #pragma unroll
            for (int ni = 0; ni < 4; ++ni)
                acc2[mi][ni] = __builtin_amdgcn_mfma_f32_16x16x32_bf16(a[mi], bb[ni], acc2[mi][ni], 0, 0, 0);
    }

    // bias + squared row-sums (this wave's 64 cols)
    float sq[4][4];
    {
        float bias2[4];
        #pragma unroll
        for (int ni = 0; ni < 4; ++ni) bias2[ni] = b2[s * CLIP + wn0 + ni * 16 + c];
        #pragma unroll
        for (int mi = 0; mi < 4; ++mi)
            #pragma unroll
            for (int i = 0; i < 4; ++i) sq[mi][i] = 0.f;
        #pragma unroll
        for (int mi = 0; mi < 4; ++mi)
            #pragma unroll
            for (int ni = 0; ni < 4; ++ni)
                #pragma unroll
                for (int i = 0; i < 4; ++i) {
                    float v = acc2[mi][ni][i] + bias2[ni];
                    acc2[mi][ni][i] = v;
                    sq[mi][i] += v * v;
                }
    }
    #pragma unroll
    for (int m = 1; m < 16; m <<= 1)
        #pragma unroll
        for (int mi = 0; mi < 4; ++mi)
            #pragma unroll
            for (int i = 0; i < 4; ++i)
                sq[mi][i] += __shfl_xor(sq[mi][i], m);

    if (c == 0) {
        #pragma unroll
        for (int mi = 0; mi < 4; ++mi)
            #pragma unroll
            for (int i = 0; i < 4; ++i)
                partial[(mi * 16 + gl * 4 + i) * 8 + wave] = sq[mi][i];
    }
    __syncthreads();
    if (tid < 64) {
        float t = 0.f;
        #pragma unroll
        for (int w = 0; w < 8; ++w) t += partial[tid * 8 + w];
        scalev[tid] = 1.f / fmaxf(sqrtf(t), 1e-12f);
    }
    __syncthreads();

    #pragma unroll
    for (int mi = 0; mi < 4; ++mi)
        #pragma unroll
        for (int i = 0; i < 4; ++i) {
            int row = mi * 16 + gl * 4 + i;
            if (row < nrows) {
                float sc = scalev[row];
                float* op = out + (size_t)rowidx[row] * CLIP + wn0 + c;
                #pragma unroll
                for (int ni = 0; ni < 4; ++ni)
                    op[ni * 16] = acc2[mi][ni][i] * sc;
            }
        }
}

extern "C" void kernel_launch(void* const* d_in, const int* in_sizes, int n_in,
                              void* d_out, int out_size, void* d_ws, size_t ws_size,
                              hipStream_t stream) {
    const float* eeg = (const float*)d_in[0];
    const int* sid   = (const int*)d_in[1];
    const float* W1  = (const float*)d_in[2];
    const float* b1  = (const float*)d_in[3];
    const float* W2  = (const float*)d_in[4];
    const float* b2  = (const float*)d_in[5];
    float* out = (float*)d_out;

    u16* w1p = (u16*)d_ws;                                   // 3.4 MB (packed)
    u16* w2p = w1p + (size_t)NSUB * CLIP * EEG;              // 6.8 MB (packed)
    u16* Hbuf = w2p + (size_t)NSUB * CLIP * CLIP;            // 16.8 MB (sorted order)
    int* meta = (int*)(Hbuf + (size_t)BATCH * CLIP);         // ~72 KB

    convert_pack<<<1248, 256, 0, stream>>>(W1, W2, w1p, w2p);
    hist_k<<<BATCH / 256, 256, 0, stream>>>(sid, meta);
    scan_k<<<1, 256, 0, stream>>>(meta);
    scatter2_k<<<BATCH / 256, 256, 0, stream>>>(sid, meta);
    gemm1_k<<<(BATCH / 128 + NSUB) * 2, 512, 0, stream>>>(eeg, b1, w1p, meta, Hbuf);
    gemm2_k<<<BATCH / 64 + NSUB, 512, 0, stream>>>(b2, w2p, meta, Hbuf, out);
}

// Round 8
// 65.167 us; speedup vs baseline: 1.6972x; 1.0099x over previous
//
#include <hip/hip_runtime.h>
#include <hip/hip_bf16.h>

// SubjectSpecificProjection: per-subject 2-layer MLP (256->512->512) + L2 normalize.
// R8: packed weights (R7, confirmed ~2x fetch-rate win) + single-round grids:
//     gemm1 M=256 x panel256 (154 blocks), gemm2 M=128 x fullN (141 blocks),
//     both 1024 thr / 16 waves / acc[4][4]. Bucketing fused: hist inside
//     convert_pack (first 64 blocks), scan+scatter one kernel. 4 launches total.

#define BATCH 16384
#define EEG 256
#define CLIP 512
#define NSUB 13

// meta layout (ints):
#define M_BCNT 0        // [64][13]
#define M_SOFF 832      // [14] sample offsets per subject
#define M_TOT  846      // [13]
#define M_C128 859      // [14] 128-row chunk offsets
#define M_C256 873      // [14] 256-row chunk offsets
#define M_IDX  896      // [16384]

typedef unsigned short u16;
typedef __attribute__((ext_vector_type(8))) short short8;
typedef __attribute__((ext_vector_type(4))) float f32x4;

__device__ __forceinline__ u16 f2bf(float f) {
    union { float f; unsigned int u; } v; v.f = f;
    unsigned int u = v.u;
    unsigned int r = (u + 0x7FFFu + ((u >> 16) & 1u)) >> 16;   // RNE
    return (u16)r;
}

// ---- weight convert + pack (R7 layout) + histogram (first 64 blocks) ----
// chunk(s,g,t) = 2048 u16 [slot(4)][colin(64)][e(8)]; element =
//   W[s][k = t*32 + slot*8 + e][n = g*64 + colin].
__global__ __launch_bounds__(256) void convert_pack(
    const float* __restrict__ W1, const float* __restrict__ W2,
    u16* __restrict__ w1p, u16* __restrict__ w2p,
    const int* __restrict__ sid, int* __restrict__ meta) {
    __shared__ u16 T[64][72];
    __shared__ int hh[NSUB];
    int b = blockIdx.x;
    const float* src; u16* dstbase; int ksteps;
    int s, kt, g;
    if (b < 416) {                     // W1: 13 x (4 kt)x(8 g)
        s = b >> 5; int t = b & 31;
        kt = t >> 3; g = t & 7;
        ksteps = 8;
        src = W1 + (size_t)s * EEG * CLIP;
        dstbase = w1p + (size_t)s * CLIP * EEG;
    } else {                           // W2: 13 x (8 kt)x(8 g)
        b -= 416; s = b >> 6; int t = b & 63;
        kt = t >> 3; g = t & 7;
        ksteps = 16;
        src = W2 + (size_t)s * CLIP * CLIP;
        dstbase = w2p + (size_t)s * CLIP * CLIP;
    }
    int k0 = kt << 6, n0 = g << 6;
    int tid = threadIdx.x;
    int rk = tid >> 2;
    int cg = (tid & 3) << 4;
    const float4* p4 = reinterpret_cast<const float4*>(src + (size_t)(k0 + rk) * CLIP + n0 + cg);
    #pragma unroll
    for (int jj = 0; jj < 4; ++jj) {
        float4 v = p4[jj];
        T[cg + jj * 4 + 0][rk] = f2bf(v.x);
        T[cg + jj * 4 + 1][rk] = f2bf(v.y);
        T[cg + jj * 4 + 2][rk] = f2bf(v.z);
        T[cg + jj * 4 + 3][rk] = f2bf(v.w);
    }
    __syncthreads();
    int colin = tid & 63, sl = (tid >> 6) & 3;
    #pragma unroll
    for (int half = 0; half < 2; ++half) {
        int t = kt * 2 + half;
        u16* dst = dstbase + ((size_t)(g * ksteps + t)) * 2048 + sl * 512 + colin * 8;
        *reinterpret_cast<short8*>(dst) =
            *reinterpret_cast<const short8*>(&T[colin][half * 32 + sl * 8]);
    }
    // fused histogram: blocks 0..63 cover BATCH = 64*256 samples
    if (blockIdx.x < 64) {
        if (tid < NSUB) hh[tid] = 0;
        __syncthreads();
        atomicAdd(&hh[sid[blockIdx.x * 256 + tid]], 1);
        __syncthreads();
        if (tid < NSUB) meta[M_BCNT + blockIdx.x * NSUB + tid] = hh[tid];
    }
}

// ---- scan + scatter in one kernel (each block redoes the cheap 64x13 scan) ----
__global__ __launch_bounds__(256) void scanscatter_k(
    const int* __restrict__ sid, int* __restrict__ meta) {
    __shared__ int cnt[64][NSUB];
    __shared__ int so[NSUB + 1], myoff[NSUB], tot[NSUB];
    __shared__ int h[NSUB];
    int tid = threadIdx.x;
    for (int i = tid; i < 64 * NSUB; i += 256)
        cnt[i / NSUB][i % NSUB] = meta[M_BCNT + i];
    if (tid < NSUB) h[tid] = 0;
    __syncthreads();
    if (tid < NSUB) {
        int run = 0, mine = 0;
        for (int b = 0; b < 64; ++b) {
            if (b == (int)blockIdx.x) mine = run;
            run += cnt[b][tid];
        }
        tot[tid] = run; myoff[tid] = mine;
    }
    __syncthreads();
    if (tid == 0) {
        int off = 0;
        for (int s = 0; s < NSUB; ++s) { so[s] = off; off += tot[s]; }
        so[NSUB] = off;
    }
    __syncthreads();
    if (blockIdx.x == 0) {
        if (tid < NSUB + 1) meta[M_SOFF + tid] = so[tid];
        if (tid < NSUB) meta[M_TOT + tid] = tot[tid];
        if (tid == 0) {
            int c128 = 0, c256 = 0;
            for (int s = 0; s < NSUB; ++s) {
                meta[M_C128 + s] = c128; meta[M_C256 + s] = c256;
                c128 += (tot[s] + 127) >> 7;
                c256 += (tot[s] + 255) >> 8;
            }
            meta[M_C128 + NSUB] = c128;
            meta[M_C256 + NSUB] = c256;
        }
    }
    int i = blockIdx.x * 256 + tid;
    int s = sid[i];
    int r = atomicAdd(&h[s], 1);
    meta[M_IDX + so[s] + myoff[s] + r] = i;
}

// ---- K1: H = relu(X @ W1 + b1). M=256 x panel=256, 1024 thr, waves 4Mx4N ----
__global__ __launch_bounds__(1024) void gemm1_k(
    const float* __restrict__ X, const float* __restrict__ b1,
    const u16* __restrict__ w1p, const int* __restrict__ meta,
    u16* __restrict__ H) {

    __shared__ u16 Xc[256 * 72];       // 36.9 KB
    __shared__ int info[4];
    __shared__ int rowidx[256];
    __shared__ int cobuf[14], sobuf[14], totbuf[NSUB];

    int tid = threadIdx.x;

    int nwg = gridDim.x;
    int q = nwg >> 3, r = nwg & 7;
    int xcd = blockIdx.x & 7, idx = blockIdx.x >> 3;
    int bid = (xcd < r) ? xcd * (q + 1) + idx : r * (q + 1) + (xcd - r) * q + idx;
    int chunk = bid >> 1, panel = bid & 1;

    if (tid < 14) { cobuf[tid] = meta[M_C256 + tid]; sobuf[tid] = meta[M_SOFF + tid]; }
    if (tid < NSUB) totbuf[tid] = meta[M_TOT + tid];
    __syncthreads();
    if (tid == 0) {
        int total = cobuf[NSUB];
        if (chunk < total) {
            int s = 0;
            while (s < NSUB && !(chunk >= cobuf[s] && chunk < cobuf[s + 1])) s++;
            int ch = chunk - cobuf[s];
            info[0] = s;
            info[1] = sobuf[s] + ch * 256;
            info[2] = min(256, totbuf[s] - ch * 256);
        } else info[0] = -1;
    }
    __syncthreads();
    if (info[0] < 0) return;
    int s = info[0], rowbase = info[1], nrows = info[2];
    if (tid < 256) rowidx[tid] = meta[M_IDX + rowbase + min(tid, nrows - 1)];

    int wave = tid >> 6, lane = tid & 63;
    int c = lane & 15, gl = lane >> 4;
    int wm = wave >> 2, wn = wave & 3;     // 4M x 4N
    int col0 = panel * 256 + wn * 64;
    const u16* w1c = w1p + (size_t)s * CLIP * EEG + (size_t)(col0 >> 6) * 8 * 2048;

    f32x4 acc[4][4];
    #pragma unroll
    for (int mi = 0; mi < 4; ++mi)
        #pragma unroll
        for (int ni = 0; ni < 4; ++ni)
            acc[mi][ni] = (f32x4){0.f, 0.f, 0.f, 0.f};

    int srow = tid >> 2, sl4 = tid & 3;    // 256 rows, 4 threads/row

    for (int kc = 0; kc < 4; ++kc) {
        __syncthreads();
        {   // stage 256x64 X chunk, fp32 -> bf16 (4 float4 per thread)
            const float4* xp = reinterpret_cast<const float4*>(
                X + (size_t)rowidx[srow] * EEG) + kc * 16 + sl4 * 4;
            u16* xd = &Xc[srow * 72 + sl4 * 16];
            #pragma unroll
            for (int j = 0; j < 4; ++j) {
                float4 v = xp[j];
                union { u16 u[4]; uint2 qq; } pk;
                pk.u[0] = f2bf(v.x); pk.u[1] = f2bf(v.y);
                pk.u[2] = f2bf(v.z); pk.u[3] = f2bf(v.w);
                *reinterpret_cast<uint2*>(&xd[j * 4]) = pk.qq;
            }
        }
        __syncthreads();
        #pragma unroll
        for (int k0 = 0; k0 < 64; k0 += 32) {
            int t = kc * 2 + (k0 >> 5);
            short8 a[4], bb[4];
            #pragma unroll
            for (int ni = 0; ni < 4; ++ni)
                bb[ni] = *reinterpret_cast<const short8*>(
                    &w1c[(size_t)t * 2048 + gl * 512 + (ni * 16 + c) * 8]);
            #pragma unroll
            for (int mi = 0; mi < 4; ++mi)
                a[mi] = *reinterpret_cast<const short8*>(
                    &Xc[(wm * 64 + mi * 16 + c) * 72 + k0 + gl * 8]);
            #pragma unroll
            for (int mi = 0; mi < 4; ++mi)
                #pragma unroll
                for (int ni = 0; ni < 4; ++ni)
                    acc[mi][ni] = __builtin_amdgcn_mfma_f32_16x16x32_bf16(a[mi], bb[ni], acc[mi][ni], 0, 0, 0);
        }
    }

    // epilogue: bias + relu -> H (sorted order, guarded rows)
    float bias1[4];
    #pragma unroll
    for (int ni = 0; ni < 4; ++ni) bias1[ni] = b1[s * CLIP + col0 + ni * 16 + c];
    #pragma unroll
    for (int mi = 0; mi < 4; ++mi)
        #pragma unroll
        for (int i = 0; i < 4; ++i) {
            int rl = wm * 64 + mi * 16 + gl * 4 + i;
            if (rl < nrows) {
                u16* hp = H + (size_t)(rowbase + rl) * CLIP + col0 + c;
                #pragma unroll
                for (int ni = 0; ni < 4; ++ni) {
                    float h = fmaxf(acc[mi][ni][i] + bias1[ni], 0.f);
                    hp[ni * 16] = f2bf(h);
                }
            }
        }
}

// ---- K2: Y = H @ W2 + b2, L2-normalize, scatter. M=128 x full N, 1024 thr ----
__global__ __launch_bounds__(1024) void gemm2_k(
    const float* __restrict__ b2, const u16* __restrict__ w2p,
    const int* __restrict__ meta, const u16* __restrict__ H,
    float* __restrict__ out) {

    __shared__ u16 Hc[128 * 72];       // 18.4 KB
    __shared__ float partial[128 * 8]; // 4 KB
    __shared__ float scalev[128];
    __shared__ int info[4];
    __shared__ int rowidx[128];
    __shared__ int cobuf[14], sobuf[14], totbuf[NSUB];

    int tid = threadIdx.x;

    int nwg = gridDim.x;
    int q = nwg >> 3, r = nwg & 7;
    int xcd = blockIdx.x & 7, idx = blockIdx.x >> 3;
    int bid = (xcd < r) ? xcd * (q + 1) + idx : r * (q + 1) + (xcd - r) * q + idx;

    if (tid < 14) { cobuf[tid] = meta[M_C128 + tid]; sobuf[tid] = meta[M_SOFF + tid]; }
    if (tid < NSUB) totbuf[tid] = meta[M_TOT + tid];
    __syncthreads();
    if (tid == 0) {
        int total = cobuf[NSUB];
        if (bid < total) {
            int s = 0;
            while (s < NSUB && !(bid >= cobuf[s] && bid < cobuf[s + 1])) s++;
            int chunk = bid - cobuf[s];
            info[0] = s;
            info[1] = sobuf[s] + chunk * 128;
            info[2] = min(128, totbuf[s] - chunk * 128);
        } else info[0] = -1;
    }
    __syncthreads();
    if (info[0] < 0) return;
    int s = info[0], rowbase = info[1], nrows = info[2];
    if (tid < 128) rowidx[tid] = meta[M_IDX + rowbase + min(tid, nrows - 1)];

    int wave = tid >> 6, lane = tid & 63;
    int c = lane & 15, gl = lane >> 4;
    int wm = wave >> 3, wn = wave & 7;     // 2M x 8N
    int wn0 = wn * 64;
    const u16* w2c = w2p + (size_t)s * CLIP * CLIP + (size_t)wn * 16 * 2048;

    f32x4 acc2[4][4];
    #pragma unroll
    for (int mi = 0; mi < 4; ++mi)
        #pragma unroll
        for (int ni = 0; ni < 4; ++ni)
            acc2[mi][ni] = (f32x4){0.f, 0.f, 0.f, 0.f};

    int srow = tid >> 3, sl8 = tid & 7;    // 128 rows, 8 threads/row, 1 short8 each

    for (int kc = 0; kc < 8; ++kc) {
        __syncthreads();
        {   // stage 128x64 H bf16 chunk
            int hrow = rowbase + min(srow, nrows - 1);
            const short8* hp = reinterpret_cast<const short8*>(
                H + (size_t)hrow * CLIP + kc * 64);
            *reinterpret_cast<short8*>(&Hc[srow * 72 + sl8 * 8]) = hp[sl8];
        }
        __syncthreads();
        #pragma unroll
        for (int k0 = 0; k0 < 64; k0 += 32) {
            int t = kc * 2 + (k0 >> 5);
            short8 a[4], bb[4];
            #pragma unroll
            for (int ni = 0; ni < 4; ++ni)
                bb[ni] = *reinterpret_cast<const short8*>(
                    &w2c[(size_t)t * 2048 + gl * 512 + (ni * 16 + c) * 8]);
            #pragma unroll
            for (int mi = 0; mi < 4; ++mi)
                a[mi] = *reinterpret_cast<const short8*>(
                    &Hc[(wm * 64 + mi * 16 + c) * 72 + k0 + gl * 8]);
            #pragma unroll
            for (int mi = 0; mi < 4; ++mi)
                #pragma unroll
                for (int ni = 0; ni < 4; ++ni)
                    acc2[mi][ni] = __builtin_amdgcn_mfma_f32_16x16x32_bf16(a[mi], bb[ni], acc2[mi][ni], 0, 0, 0);
        }
    }

    // bias + squared row-sums (this wave's 64 cols of its 64 rows)
    float sq[4][4];
    {
        float bias2[4];
        #pragma unroll
        for (int ni = 0; ni < 4; ++ni) bias2[ni] = b2[s * CLIP + wn0 + ni * 16 + c];
        #pragma unroll
        for (int mi = 0; mi < 4; ++mi)
            #pragma unroll
            for (int i = 0; i < 4; ++i) sq[mi][i] = 0.f;
        #pragma unroll
        for (int mi = 0; mi < 4; ++mi)
            #pragma unroll
            for (int ni = 0; ni < 4; ++ni)
                #pragma unroll
                for (int i = 0; i < 4; ++i) {
                    float v = acc2[mi][ni][i] + bias2[ni];
                    acc2[mi][ni][i] = v;
                    sq[mi][i] += v * v;
                }
    }
    #pragma unroll
    for (int m = 1; m < 16; m <<= 1)
        #pragma unroll
        for (int mi = 0; mi < 4; ++mi)
            #pragma unroll
            for (int i = 0; i < 4; ++i)
                sq[mi][i] += __shfl_xor(sq[mi][i], m);

    if (c == 0) {
        #pragma unroll
        for (int mi = 0; mi < 4; ++mi)
            #pragma unroll
            for (int i = 0; i < 4; ++i)
                partial[(wm * 64 + mi * 16 + gl * 4 + i) * 8 + wn] = sq[mi][i];
    }
    __syncthreads();
    if (tid < 128) {
        float t = 0.f;
        #pragma unroll
        for (int w = 0; w < 8; ++w) t += partial[tid * 8 + w];
        scalev[tid] = 1.f / fmaxf(sqrtf(t), 1e-12f);
    }
    __syncthreads();

    #pragma unroll
    for (int mi = 0; mi < 4; ++mi)
        #pragma unroll
        for (int i = 0; i < 4; ++i) {
            int row = wm * 64 + mi * 16 + gl * 4 + i;
            if (row < nrows) {
                float sc = scalev[row];
                float* op = out + (size_t)rowidx[row] * CLIP + wn0 + c;
                #pragma unroll
                for (int ni = 0; ni < 4; ++ni)
                    op[ni * 16] = acc2[mi][ni][i] * sc;
            }
        }
}

extern "C" void kernel_launch(void* const* d_in, const int* in_sizes, int n_in,
                              void* d_out, int out_size, void* d_ws, size_t ws_size,
                              hipStream_t stream) {
    const float* eeg = (const float*)d_in[0];
    const int* sid   = (const int*)d_in[1];
    const float* W1  = (const float*)d_in[2];
    const float* b1  = (const float*)d_in[3];
    const float* W2  = (const float*)d_in[4];
    const float* b2  = (const float*)d_in[5];
    float* out = (float*)d_out;

    u16* w1p = (u16*)d_ws;                                   // 3.4 MB (packed)
    u16* w2p = w1p + (size_t)NSUB * CLIP * EEG;              // 6.8 MB (packed)
    u16* Hbuf = w2p + (size_t)NSUB * CLIP * CLIP;            // 16.8 MB (sorted order)
    int* meta = (int*)(Hbuf + (size_t)BATCH * CLIP);         // ~68 KB

    convert_pack<<<1248, 256, 0, stream>>>(W1, W2, w1p, w2p, sid, meta);
    scanscatter_k<<<64, 256, 0, stream>>>(sid, meta);
    gemm1_k<<<(BATCH / 256 + NSUB) * 2, 1024, 0, stream>>>(eeg, b1, w1p, meta, Hbuf);
    gemm2_k<<<BATCH / 128 + NSUB, 1024, 0, stream>>>(b2, w2p, meta, Hbuf, out);
}